// Round 7
// baseline (130.366 us; speedup 1.0000x reference)
//
#include <hip/hip_runtime.h>
#include <hip/hip_bf16.h>
#include <stdint.h>

// out = X @ Bbig + bias; X = (32768 x 1024) fp32 (real||imag)
//   n<512:  B[k][n] = Wr[n][k] (k<512), -Wi[n][k-512] (k>=512)
//   n>=512: B[k][n] = Wi[n-512][k] (k<512), Wr[n-512][k-512] (k>=512)
// Structure (R7): pre-swizzled fp16 images for A and B; GEMM 256x256/BK=64,
// 8 waves (2Mx4N), ONE phase per K-tile:
//   {24 frag ds_reads | lgkmcnt(0) | BAR | stage(t+2): 8 gload_lds |
//    64 MFMA under setprio | vmcnt(8) | BAR}
// Rationale: R3 (4-phase) == R6 (8-phase) == ~100us showed per-phase sync
// overhead (~1250cyc) dominates; with 2 waves/SIMD (VGPR-capped) the fix is
// fewer, bigger phases: 2 barriers per K-tile instead of 8.

typedef _Float16 half8 __attribute__((ext_vector_type(8)));
typedef _Float16 half4v __attribute__((ext_vector_type(4)));
typedef float f32x4 __attribute__((ext_vector_type(4)));

typedef __attribute__((address_space(3))) void* lds_ptr_t;
typedef const __attribute__((address_space(1))) void* gbl_ptr_t;

__device__ __forceinline__ void gload_lds16(const void* g, void* s) {
  // lane l's 16B from per-lane g land at (wave-uniform) s + l*16
  __builtin_amdgcn_global_load_lds((gbl_ptr_t)g, (lds_ptr_t)s, 16, 0, 0);
}

#define BARF() asm volatile("s_barrier" ::: "memory")
#define LGKM0() asm volatile("s_waitcnt lgkmcnt(0)" ::: "memory")
#define VMC8() asm volatile("s_waitcnt vmcnt(8)" ::: "memory")
#define VMC0() asm volatile("s_waitcnt vmcnt(0)" ::: "memory")
#define PRIO1() __builtin_amdgcn_s_setprio(1)
#define PRIO0() __builtin_amdgcn_s_setprio(0)

// Tile byte layout (32 KB per 256-row x 64-col fp16 tile):
//   byte = row*128 + ((kcol*2) ^ ((row&7)<<4))   -- XOR bank swizzle

// ---------------- Kernel 1: swizzled B image (validated r2-r6) ----------------
__global__ void build_bt(const float* __restrict__ G1R, const float* __restrict__ G2R,
                         const float* __restrict__ G1I, const float* __restrict__ G2I,
                         _Float16* __restrict__ BTimg) {
  int idx = blockIdx.x * 256 + threadIdx.x;  // 0 .. 1M-1
  int kcol = idx & 63;
  int row  = (idx >> 6) & 255;
  int kt   = (idx >> 14) & 15;
  int nt   = idx >> 18;
  int n = nt * 256 + row;
  int k = kt * 64 + kcol;
  int o = n & 511, i = k & 511;
  bool imagOut = n >= 512, kHi = k >= 512;
  const float* G1; const float* G2; float sign = 1.0f;
  if (imagOut == kHi) { G1 = G1R; G2 = G2R; }
  else { G1 = G1I; G2 = G2I; if (!imagOut) sign = -1.0f; }
  int b = o >> 4, e = o & 15, d = i >> 4, g = i & 15;
  float w = 0.0f;
#pragma unroll
  for (int c = 0; c < 4; ++c)
    w += G1[b * 128 + c * 32 + d] * G2[c * 256 + e * 16 + g];
  size_t byteoff = ((size_t)(nt * 16 + kt) << 15) + (size_t)row * 128
                 + ((kcol * 2) ^ ((row & 7) << 4));
  *(_Float16*)((char*)BTimg + byteoff) = (_Float16)(sign * w);
}

// ---------------- Kernel 2: X fp32 -> swizzled fp16 A image (validated r3/r6) --
__global__ __launch_bounds__(256) void build_at(const float* __restrict__ A,
                                                _Float16* __restrict__ Aimg) {
  const int tid = threadIdx.x;
  const int kt = blockIdx.x & 15, mt = blockIdx.x >> 4;
  const float* src = A + (size_t)mt * 256 * 1024 + kt * 64;
  char* dst = (char*)Aimg + ((size_t)(mt * 16 + kt) << 15);
  const int cg = tid & 15;        // col group (4 floats)
  const int rb = tid >> 4;        // row base
#pragma unroll
  for (int r = 0; r < 16; ++r) {
    int row = rb + r * 16;        // 0..255
    float4 v = *(const float4*)(src + (size_t)row * 1024 + cg * 4);
    half4v h = { (_Float16)v.x, (_Float16)v.y, (_Float16)v.z, (_Float16)v.w };
    *(half4v*)(dst + row * 128 + ((cg * 8) ^ ((row & 7) << 4))) = h;
  }
}

// ---------------- Kernel 3: GEMM, 1-phase-per-K-tile, counted vmcnt ----------
__global__ __launch_bounds__(512, 2) void tt_gemm(
    const _Float16* __restrict__ Aimg, const _Float16* __restrict__ Bimg,
    const float* __restrict__ bias_r, const float* __restrict__ bias_i,
    float* __restrict__ C) {
  __shared__ __align__(16) _Float16 Als[2][16384];  // 32KB/buf, swizzled
  __shared__ __align__(16) _Float16 Bls[2][16384];

  const int tid = threadIdx.x;
  const int bid = blockIdx.x;
  // XCD swizzle (512 % 8 == 0): 64 contiguous per XCD, nt fastest (A L2 reuse)
  const int bid2 = (bid & 7) * 64 + (bid >> 3);
  const int mt = bid2 >> 2, nt = bid2 & 3;

  const int lane = tid & 63, wid = tid >> 6;
  const int wm = wid >> 2, wn = wid & 3;   // wave -> 128(M) x 64(N) C subtile
  const int lr = lane & 15, lq = lane >> 4;

  f32x4 acc[8][4] = {};
  half8 afr[8][2];   // mf 0..7 -> rows wm*128 + mf*16 + lr ; kk = K-half
  half8 bfr[4][2];   // j  0..3 -> rows wn*64  + j*16  + lr

  const char* Abase = (const char*)Aimg + ((size_t)mt << 19);  // 16 tiles*32KB
  const char* Bbase = (const char*)Bimg + ((size_t)nt << 19);
  const int qoff = wid * 1024 + lane * 16;   // this wave's slice of a quarter

  auto stageT = [&](int t, _Float16* Abuf, _Float16* Bbuf) {  // 8 gload/wave
    const char* sa = Abase + ((size_t)t << 15) + qoff;
    const char* sb = Bbase + ((size_t)t << 15) + qoff;
#pragma unroll
    for (int q = 0; q < 4; ++q)
      gload_lds16(sa + q * 8192, (char*)Abuf + q * 8192 + wid * 1024);
#pragma unroll
    for (int q = 0; q < 4; ++q)
      gload_lds16(sb + q * 8192, (char*)Bbuf + q * 8192 + wid * 1024);
  };
  auto fragReads = [&](const _Float16* Abuf, const _Float16* Bbuf) {
#pragma unroll
    for (int mf = 0; mf < 8; ++mf)
#pragma unroll
      for (int kk = 0; kk < 2; ++kk) {
        int row = wm * 128 + mf * 16 + lr;
        int byte = row * 128 + ((kk * 64 + lq * 16) ^ ((row & 7) << 4));
        afr[mf][kk] = *(const half8*)((const char*)Abuf + byte);
      }
#pragma unroll
    for (int j = 0; j < 4; ++j)
#pragma unroll
      for (int kk = 0; kk < 2; ++kk) {
        int row = wn * 64 + j * 16 + lr;
        int byte = row * 128 + ((kk * 64 + lq * 16) ^ ((row & 7) << 4));
        bfr[j][kk] = *(const half8*)((const char*)Bbuf + byte);
      }
  };
  auto mmaAll = [&]() {   // 64 MFMA, 32 independent 2-chains
#pragma unroll
    for (int mf = 0; mf < 8; ++mf)
#pragma unroll
      for (int j = 0; j < 4; ++j)
#pragma unroll
        for (int kk = 0; kk < 2; ++kk)
          acc[mf][j] = __builtin_amdgcn_mfma_f32_16x16x32_f16(
              afr[mf][kk], bfr[j][kk], acc[mf][j], 0, 0, 0);
  };

  // ---- prologue: T0 and T1 fully staged; T1 stays in flight ----
  stageT(0, Als[0], Bls[0]);   // 8 vmem (oldest)
  stageT(1, Als[1], Bls[1]);   // 8 vmem
  VMC8();                      // T0 landed; T1 in flight
  BARF();

  // ---- main loop: 16 K-tiles, one phase each ----
#pragma unroll 2
  for (int t = 0; t < 16; ++t) {
    const int c = t & 1;
    fragReads(Als[c], Bls[c]);   // 24 ds_read_b128
    LGKM0();                     // frags in regs -> buf c reusable after BAR
    BARF();
    if (t < 14) stageT(t + 2, Als[c], Bls[c]);  // overwrite freed buf c
    PRIO1(); mmaAll(); PRIO0();
    if (t < 14) { VMC8(); }      // complete stage(t+1); stage(t+2) stays
    else if (t == 14) { VMC0(); }
    if (t < 15) BARF();
  }

  // ---- epilogue: C/D layout col=lr, row=lq*4+r ----
  const int row0 = mt * 256, col0 = nt * 256;
#pragma unroll
  for (int fn = 0; fn < 4; ++fn) {
    int col = col0 + wn * 64 + fn * 16 + lr;
    float bias = (col < 512) ? bias_r[col] : bias_i[col - 512];
#pragma unroll
    for (int fm = 0; fm < 8; ++fm) {
      int r0 = row0 + wm * 128 + fm * 16 + lq * 4;
#pragma unroll
      for (int r = 0; r < 4; ++r)
        C[(size_t)(r0 + r) * 1024 + col] = acc[fm][fn][r] + bias;
    }
  }
}

extern "C" void kernel_launch(void* const* d_in, const int* in_sizes, int n_in,
                              void* d_out, int out_size, void* d_ws, size_t ws_size,
                              hipStream_t stream) {
  const float* x   = (const float*)d_in[0];
  const float* G1R = (const float*)d_in[1];
  const float* G2R = (const float*)d_in[2];
  const float* G1I = (const float*)d_in[3];
  const float* G2I = (const float*)d_in[4];
  const float* br  = (const float*)d_in[5];
  const float* bi  = (const float*)d_in[6];
  float* out = (float*)d_out;

  _Float16* Bimg = (_Float16*)d_ws;                          // 2 MB
  _Float16* Aimg = (_Float16*)((char*)d_ws + (2u << 20));    // 64 MB

  build_bt<<<4096, 256, 0, stream>>>(G1R, G2R, G1I, G2I, Bimg);
  build_at<<<2048, 256, 0, stream>>>(x, Aimg);
  tt_gemm<<<512, 512, 0, stream>>>(Aimg, Bimg, br, bi, out);
}

// Round 9
// 125.044 us; speedup vs baseline: 1.0426x; 1.0426x over previous
//
#include <hip/hip_runtime.h>
#include <hip/hip_bf16.h>
#include <stdint.h>

// out = X @ Bbig + bias; X = (32768 x 1024) fp32 (real||imag)
//   n<512:  B[k][n] = Wr[n][k] (k<512), -Wi[n][k-512] (k>=512)
//   n>=512: B[k][n] = Wi[n-512][k] (k<512), Wr[n-512][k-512] (k>=512)
// R9 = R8 (fused m97-clone, 3 blocks/CU) + vmem issue-order fences.
//   128x128 tile, BK=32, 256 thr (4 waves 2x2), LDS 32 KB, launch_bounds(256,3).
//   B: flat fp16 tile image (2 MB, L2-resident) via global_load_lds.
//   A: x fp32 -> regs (prefetch 2 K-steps deep) -> cvt -> ds_write_b128.
//   Counted vmcnt(4)/iter. CRITICAL: empty memory-clobber asm between each
//   vmem issue group pins the FIFO order the ledger assumes (R8's NaN was
//   the compiler reordering aload ahead of the gload_lds builtins).

typedef _Float16 half8 __attribute__((ext_vector_type(8)));
typedef float f32x4 __attribute__((ext_vector_type(4)));

typedef __attribute__((address_space(3))) void* lds_ptr_t;
typedef const __attribute__((address_space(1))) void* gbl_ptr_t;

__device__ __forceinline__ void gload_lds16(const void* g, void* s) {
  // lane l's 16B from per-lane g land at (wave-uniform) s + l*16
  __builtin_amdgcn_global_load_lds((gbl_ptr_t)g, (lds_ptr_t)s, 16, 0, 0);
}

#define BARF() asm volatile("s_barrier" ::: "memory")
#define LGKM0() asm volatile("s_waitcnt lgkmcnt(0)" ::: "memory")
#define VMC4() asm volatile("s_waitcnt vmcnt(4)" ::: "memory")
#define VMC0() asm volatile("s_waitcnt vmcnt(0)" ::: "memory")
#define FENCE() asm volatile("" ::: "memory")   // pins vmem issue order, 0 cost

// ---------------- Kernel 1: flat B^T tile image (validated r8 build) ---------
// BT[nt 0..7][kt 0..31][row 0..127][col 0..31] fp16, fully linear:
//   elem offset = (nt<<17) | (kt<<12) | (row<<5) | col
__global__ void build_bt(const float* __restrict__ G1R, const float* __restrict__ G2R,
                         const float* __restrict__ G1I, const float* __restrict__ G2I,
                         _Float16* __restrict__ BT) {
  int idx = blockIdx.x * 256 + threadIdx.x;  // 0 .. 1M-1
  int col = idx & 31;
  int row = (idx >> 5) & 127;
  int kt  = (idx >> 12) & 31;
  int nt  = idx >> 17;
  int n = nt * 128 + row;
  int k = kt * 32 + col;
  int o = n & 511, i = k & 511;
  bool imagOut = n >= 512, kHi = k >= 512;
  const float* G1; const float* G2; float sign = 1.0f;
  if (imagOut == kHi) { G1 = G1R; G2 = G2R; }
  else { G1 = G1I; G2 = G2I; if (!imagOut) sign = -1.0f; }
  int b = o >> 4, e = o & 15, d = i >> 4, g = i & 15;
  float w = 0.0f;
#pragma unroll
  for (int c = 0; c < 4; ++c)
    w += G1[b * 128 + c * 32 + d] * G2[c * 256 + e * 16 + g];
  BT[idx] = (_Float16)(sign * w);
}

// ---------------- Kernel 2: fused GEMM ----------------
__global__ __launch_bounds__(256, 3) void tt_gemm(
    const float* __restrict__ A,       // 32768 x 1024 fp32 (x)
    const _Float16* __restrict__ Bimg, // flat tiled B^T image, 2 MB
    const float* __restrict__ bias_r, const float* __restrict__ bias_i,
    float* __restrict__ C) {
  __shared__ __align__(16) _Float16 Als[2][4096];  // [buf][128 r][32 k] linear
  __shared__ __align__(16) _Float16 Bls[2][4096];

  const int tid = threadIdx.x;
  const int bid = blockIdx.x;
  // XCD swizzle: 2048 blocks -> 256 contiguous per XCD, nt fastest so the
  // 8 blocks sharing an A panel (512 KB) are co-XCD and concurrent.
  const int bid2 = (bid & 7) * 256 + (bid >> 3);
  const int mt = bid2 >> 3, nt = bid2 & 7;
  const int row0 = mt * 128, col0 = nt * 128;

  const int lane = tid & 63, wid = tid >> 6;
  const int wm = wid >> 1, wn = wid & 1;   // wave -> 64x64 C subtile
  const int lr = lane & 15, lq = lane >> 4;

  f32x4 acc[4][4] = {};
  float4 areg[4];
  half8 afr[4], bfr[4];

  const float* Abase = A + (size_t)row0 * 1024;
  const char* Bbase = (const char*)Bimg + ((size_t)nt << 18);  // nt*131072 elem *2B
  const int arow = tid >> 1;           // 0..127
  const int ahalf = (tid & 1) * 16;    // float col offset: 0 or 16

  auto aload = [&](int kt) {           // 4 x global_load_dwordx4, 128B-line clean
#pragma unroll
    for (int q = 0; q < 4; ++q)
      areg[q] = *(const float4*)(Abase + (size_t)arow * 1024 + kt * 32 + ahalf + q * 4);
  };
  auto awrite = [&](_Float16* buf) {   // cvt 16 floats -> 2 x ds_write_b128
    half8 h0 = { (_Float16)areg[0].x, (_Float16)areg[0].y, (_Float16)areg[0].z, (_Float16)areg[0].w,
                 (_Float16)areg[1].x, (_Float16)areg[1].y, (_Float16)areg[1].z, (_Float16)areg[1].w };
    half8 h1 = { (_Float16)areg[2].x, (_Float16)areg[2].y, (_Float16)areg[2].z, (_Float16)areg[2].w,
                 (_Float16)areg[3].x, (_Float16)areg[3].y, (_Float16)areg[3].z, (_Float16)areg[3].w };
    char* d = (char*)buf + arow * 64 + ahalf * 2;
    *(half8*)d = h0;
    *(half8*)(d + 16) = h1;
  };
  auto bstage = [&](int kt, _Float16* buf) {  // 8KB tile, 2 gload_lds per wave
    const char* s = Bbase + kt * 8192 + wid * 1024 + lane * 16;
    char* d = (char*)buf + wid * 1024;
    gload_lds16(s, d);
    gload_lds16(s + 4096, d + 4096);
  };
  auto frd = [&](const _Float16* Ab, const _Float16* Bb) {
#pragma unroll
    for (int mf = 0; mf < 4; ++mf)
      afr[mf] = *(const half8*)((const char*)Ab + (wm * 64 + mf * 16 + lr) * 64 + lq * 16);
#pragma unroll
    for (int nf = 0; nf < 4; ++nf)
      bfr[nf] = *(const half8*)((const char*)Bb + (wn * 64 + nf * 16 + lr) * 64 + lq * 16);
  };

  // ---- prologue (vmem FIFO: aload(0)x4 | bstage(0)x2 | aload(1)x4) ----
  aload(0);                // 4 vmem
  FENCE();
  awrite(Als[0]);          // compiler-inserted vmcnt(0) drains aload(0)
  bstage(0, Bls[0]);       // 2 vmem
  FENCE();
  aload(1);                // 4 vmem (stays in flight across the barrier)
  VMC4();                  // retires bstage(0); aload(1) flies
  LGKM0();                 // A(0) ds_writes done
  BARF();

  // ---- main loop: 32 K-steps ----
  for (int kt = 0; kt < 32; ++kt) {
    const int c = kt & 1, o = c ^ 1;
    frd(Als[c], Bls[c]);                       // 8 ds_read_b128
    if (kt < 31) {
      awrite(Als[o]);                          // uses areg = x(kt+1); compiler
      bstage(kt + 1, Bls[o]);                  //   waits its vmcnt dep mid-phase
    }
    FENCE();                                   // pin: bstage before aload
    if (kt < 30) aload(kt + 2);                // deep prefetch, never drained here
    FENCE();
#pragma unroll
    for (int mf = 0; mf < 4; ++mf)
#pragma unroll
      for (int nf = 0; nf < 4; ++nf)
        acc[mf][nf] = __builtin_amdgcn_mfma_f32_16x16x32_f16(
            afr[mf], bfr[nf], acc[mf][nf], 0, 0, 0);
    if (kt < 30) { VMC4(); }                   // retires bstage(kt+1); aload(kt+2) flies
    else if (kt == 30) { VMC0(); }             // tail: only bstage(31) outstanding
    if (kt < 31) { LGKM0(); BARF(); }          // own frag reads + awrites drained
  }

  // ---- epilogue: C/D layout col=lane&15, row=(lane>>4)*4+reg ----
#pragma unroll
  for (int nf = 0; nf < 4; ++nf) {
    int col = col0 + wn * 64 + nf * 16 + lr;
    float bias = (col < 512) ? bias_r[col] : bias_i[col - 512];
#pragma unroll
    for (int mf = 0; mf < 4; ++mf) {
      int r0 = row0 + wm * 64 + mf * 16 + lq * 4;
#pragma unroll
      for (int r = 0; r < 4; ++r)
        C[(size_t)(r0 + r) * 1024 + col] = acc[mf][nf][r] + bias;
    }
  }
}

extern "C" void kernel_launch(void* const* d_in, const int* in_sizes, int n_in,
                              void* d_out, int out_size, void* d_ws, size_t ws_size,
                              hipStream_t stream) {
  const float* x   = (const float*)d_in[0];
  const float* G1R = (const float*)d_in[1];
  const float* G2R = (const float*)d_in[2];
  const float* G1I = (const float*)d_in[3];
  const float* G2I = (const float*)d_in[4];
  const float* br  = (const float*)d_in[5];
  const float* bi  = (const float*)d_in[6];
  float* out = (float*)d_out;
  _Float16* BT = (_Float16*)d_ws;  // 2 MB flat tiled B^T image

  build_bt<<<4096, 256, 0, stream>>>(G1R, G2R, G1I, G2I, BT);
  tt_gemm<<<2048, 256, 0, stream>>>(x, BT, br, bi, out);
}